// Round 1
// baseline (421.747 us; speedup 1.0000x reference)
//
#include <hip/hip_runtime.h>
#include <cfloat>
#include <math.h>

#define D_IN 128
#define D_OUT 64
#define NEG_SLOPE 0.2f

// ---------------------------------------------------------------------------
// Kernel A: H = X @ W + b.   X:[R,128] f32, W:[128,64], b:[64], H:[R,64]
// One wave per row; lane = output column. W staged in LDS (32 KB).
// X row read with wave-uniform float4 loads -> scalar loads (s_load_dwordx4).
// ---------------------------------------------------------------------------
__global__ __launch_bounds__(256) void linear_kernel(
    const float* __restrict__ X, const float* __restrict__ W,
    const float* __restrict__ b, float* __restrict__ H, int R) {
  __shared__ float Wl[D_IN * D_OUT];  // 32 KB
  __shared__ float bl[D_OUT];
  for (int i = threadIdx.x; i < D_IN * D_OUT / 4; i += 256)
    reinterpret_cast<float4*>(Wl)[i] = reinterpret_cast<const float4*>(W)[i];
  if (threadIdx.x < D_OUT) bl[threadIdx.x] = b[threadIdx.x];
  __syncthreads();

  const int wave = threadIdx.x >> 6;
  const int lane = threadIdx.x & 63;
  const int wavesTotal = gridDim.x * 4;
  for (int r = blockIdx.x * 4 + wave; r < R; r += wavesTotal) {
    const float4* xr = reinterpret_cast<const float4*>(X + (size_t)r * D_IN);
    float acc = bl[lane];
#pragma unroll 8
    for (int k4 = 0; k4 < D_IN / 4; ++k4) {
      float4 xv = xr[k4];  // wave-uniform address -> scalar load
      acc += xv.x * Wl[(k4 * 4 + 0) * D_OUT + lane];
      acc += xv.y * Wl[(k4 * 4 + 1) * D_OUT + lane];
      acc += xv.z * Wl[(k4 * 4 + 2) * D_OUT + lane];
      acc += xv.w * Wl[(k4 * 4 + 3) * D_OUT + lane];
    }
    H[(size_t)r * D_OUT + lane] = acc;
  }
}

// ---------------------------------------------------------------------------
// Kernel B: CSR row pointers from sorted dst. row_ptr[i] = lower_bound(dst, i)
// ---------------------------------------------------------------------------
__global__ void rowptr_kernel(const int* __restrict__ dst, int E, int N,
                              int* __restrict__ row_ptr) {
  int i = blockIdx.x * blockDim.x + threadIdx.x;
  if (i > N) return;
  int lo = 0, hi = E;
  while (lo < hi) {
    int mid = (lo + hi) >> 1;
    if (dst[mid] < i) lo = mid + 1; else hi = mid;
  }
  row_ptr[i] = lo;
}

// ---------------------------------------------------------------------------
// Kernel C: per-(batch,node) segmented online-softmax aggregation.
// One wave per (b,node); lane d owns output dim d. dst sorted -> CSR range.
// Per edge: coalesced 256B gathers of hk[src] / hv[src]; dot via 6-step
// __shfl_xor butterfly; online softmax (m,l,acc) in registers.
// ---------------------------------------------------------------------------
__global__ __launch_bounds__(256) void aggregate_kernel(
    const float* __restrict__ hk, const float* __restrict__ hv,
    const int* __restrict__ src, const int* __restrict__ row_ptr,
    float* __restrict__ out, int N, int B) {
  const int w = blockIdx.x * 4 + (threadIdx.x >> 6);
  const int lane = threadIdx.x & 63;
  const int total = B * N;
  if (w >= total) return;
  const int b = w / N;
  const int node = w - b * N;
  const float* hkb = hk + (size_t)b * N * D_OUT;
  const float* hvb = hv + (size_t)b * N * D_OUT;

  const float kd = hkb[(size_t)node * D_OUT + lane];
  const int e0 = row_ptr[node];
  const int e1 = row_ptr[node + 1];

  float m = -FLT_MAX, l = 0.f, acc = 0.f;
  for (int e = e0; e < e1; ++e) {
    const int s = src[e];  // wave-uniform -> scalar load
    const float ks = hkb[(size_t)s * D_OUT + lane];
    const float vs = hvb[(size_t)s * D_OUT + lane];
    float p = ks * kd;
#pragma unroll
    for (int off = 32; off >= 1; off >>= 1) p += __shfl_xor(p, off, 64);
    if (p > m) {  // rescale running state
      const float sc = __expf(m - p);  // exp(-FLT_MAX-...) -> 0 on first edge
      l *= sc; acc *= sc; m = p;
    }
    const float a = __expf(p - m);
    l += a;
    acc += a * vs;
  }
  const float denom = (l == 0.f) ? 1.f : l;
  float o = acc / denom;
  o = (o >= 0.f) ? o : NEG_SLOPE * o;
  out[(size_t)w * D_OUT + lane] = o;
}

// ---------------------------------------------------------------------------
extern "C" void kernel_launch(void* const* d_in, const int* in_sizes, int n_in,
                              void* d_out, int out_size, void* d_ws,
                              size_t ws_size, hipStream_t stream) {
  const float* X_key   = (const float*)d_in[0];
  const float* X_value = (const float*)d_in[1];
  const float* Wk      = (const float*)d_in[2];
  const float* bk      = (const float*)d_in[3];
  const float* Wv      = (const float*)d_in[4];
  const float* bv      = (const float*)d_in[5];
  const int*   src     = (const int*)d_in[6];
  const int*   dst     = (const int*)d_in[7];
  float* out = (float*)d_out;

  const int B = 2;
  const int R = in_sizes[0] / D_IN;  // B*N rows
  const int N = R / B;
  const int E = in_sizes[6];

  // workspace layout: hk [R*64] f32 | hv [R*64] f32 | row_ptr [N+1] i32
  float* hk = (float*)d_ws;
  float* hv = hk + (size_t)R * D_OUT;
  int* row_ptr = (int*)(hv + (size_t)R * D_OUT);

  const int blocksA = 1024;  // 4096 waves, grid-stride; 4 blocks/CU resident
  hipLaunchKernelGGL(linear_kernel, dim3(blocksA), dim3(256), 0, stream,
                     X_key, Wk, bk, hk, R);
  hipLaunchKernelGGL(linear_kernel, dim3(blocksA), dim3(256), 0, stream,
                     X_value, Wv, bv, hv, R);
  const int blocksB = (N + 1 + 255) / 256;
  hipLaunchKernelGGL(rowptr_kernel, dim3(blocksB), dim3(256), 0, stream,
                     dst, E, N, row_ptr);
  const int blocksC = (R + 3) / 4;  // one wave per (b,node)
  hipLaunchKernelGGL(aggregate_kernel, dim3(blocksC), dim3(256), 0, stream,
                     hk, hv, src, row_ptr, out, N, B);
}

// Round 2
// 416.008 us; speedup vs baseline: 1.0138x; 1.0138x over previous
//
#include <hip/hip_runtime.h>
#include <cfloat>
#include <math.h>

#define D_IN 128
#define D_OUT 64
#define NEG_SLOPE 0.2f
#define RPW 8  // rows per wave in linear kernel

// ---------------------------------------------------------------------------
// Kernel A: H = X @ W + b.   X:[R,128] f32, W:[128,64], b:[64], H:[R,64]
// 8 rows per wave; lane = output column. Each W element is ds_read once per
// k-quad and reused across 8 rows (ds_reads/row: 128 -> 16).
// ---------------------------------------------------------------------------
__global__ __launch_bounds__(256) void linear_kernel(
    const float* __restrict__ X, const float* __restrict__ W,
    const float* __restrict__ b, float* __restrict__ H, int R) {
  __shared__ float Wl[D_IN * D_OUT];  // 32 KB
  __shared__ float bl[D_OUT];
  for (int i = threadIdx.x; i < D_IN * D_OUT / 4; i += 256)
    reinterpret_cast<float4*>(Wl)[i] = reinterpret_cast<const float4*>(W)[i];
  if (threadIdx.x < D_OUT) bl[threadIdx.x] = b[threadIdx.x];
  __syncthreads();

  const int wave = threadIdx.x >> 6;
  const int lane = threadIdx.x & 63;
  const int r0 = (blockIdx.x * 4 + wave) * RPW;
  if (r0 >= R) return;

  if (r0 + RPW <= R) {
    float acc[RPW];
#pragma unroll
    for (int i = 0; i < RPW; ++i) acc[i] = bl[lane];
    for (int k4 = 0; k4 < D_IN / 4; ++k4) {
      float4 xv[RPW];
#pragma unroll
      for (int i = 0; i < RPW; ++i)
        xv[i] = *reinterpret_cast<const float4*>(X + (size_t)(r0 + i) * D_IN + k4 * 4);
      const float w0 = Wl[(k4 * 4 + 0) * D_OUT + lane];
      const float w1 = Wl[(k4 * 4 + 1) * D_OUT + lane];
      const float w2 = Wl[(k4 * 4 + 2) * D_OUT + lane];
      const float w3 = Wl[(k4 * 4 + 3) * D_OUT + lane];
#pragma unroll
      for (int i = 0; i < RPW; ++i)
        acc[i] += xv[i].x * w0 + xv[i].y * w1 + xv[i].z * w2 + xv[i].w * w3;
    }
#pragma unroll
    for (int i = 0; i < RPW; ++i)
      H[(size_t)(r0 + i) * D_OUT + lane] = acc[i];
  } else {
    // tail (not hit for R=100000, kept for safety)
    for (int r = r0; r < R; ++r) {
      float acc = bl[lane];
      for (int k4 = 0; k4 < D_IN / 4; ++k4) {
        float4 xv = *reinterpret_cast<const float4*>(X + (size_t)r * D_IN + k4 * 4);
        acc += xv.x * Wl[(k4 * 4 + 0) * D_OUT + lane];
        acc += xv.y * Wl[(k4 * 4 + 1) * D_OUT + lane];
        acc += xv.z * Wl[(k4 * 4 + 2) * D_OUT + lane];
        acc += xv.w * Wl[(k4 * 4 + 3) * D_OUT + lane];
      }
      H[(size_t)r * D_OUT + lane] = acc;
    }
  }
}

// ---------------------------------------------------------------------------
// Kernel B: CSR row pointers from sorted dst. row_ptr[i] = lower_bound(dst, i)
// ---------------------------------------------------------------------------
__global__ void rowptr_kernel(const int* __restrict__ dst, int E, int N,
                              int* __restrict__ row_ptr) {
  int i = blockIdx.x * blockDim.x + threadIdx.x;
  if (i > N) return;
  int lo = 0, hi = E;
  while (lo < hi) {
    int mid = (lo + hi) >> 1;
    if (dst[mid] < i) lo = mid + 1; else hi = mid;
  }
  row_ptr[i] = lo;
}

// ---------------------------------------------------------------------------
// Kernel C: per-(batch,node) segmented online-softmax aggregation.
// One wave per (b,node); 4 groups of 16 lanes, each group owns every 4th
// edge with its own online-softmax state (4x ILP on the serial chain).
// Lane holds float4 of dims (16 lanes x 4 = 64). Dot reduce = 4 shfl steps.
// Branchless online update; 2-step cross-group state merge at the end.
// ---------------------------------------------------------------------------
__global__ __launch_bounds__(256) void aggregate_kernel(
    const float* __restrict__ hk, const float* __restrict__ hv,
    const int* __restrict__ src, const int* __restrict__ row_ptr,
    float* __restrict__ out, int N, int B) {
  const int w = blockIdx.x * 4 + (threadIdx.x >> 6);
  const int lane = threadIdx.x & 63;
  if (w >= B * N) return;
  int b = 0, node = w;
  while (node >= N) { node -= N; ++b; }
  const float* hkb = hk + (size_t)b * N * D_OUT;
  const float* hvb = hv + (size_t)b * N * D_OUT;

  const int li = lane & 15;  // dim-quad index
  const int g = lane >> 4;   // edge group

  const float4 kd = *reinterpret_cast<const float4*>(
      hkb + (size_t)node * D_OUT + 4 * li);
  const int e0 = row_ptr[node];
  const int e1 = row_ptr[node + 1];

  float m = -FLT_MAX, l = 0.f;
  float4 acc = {0.f, 0.f, 0.f, 0.f};
  for (int e = e0 + g; e < e1; e += 4) {
    const int s = src[e];
    const float4 ks = *reinterpret_cast<const float4*>(
        hkb + (size_t)s * D_OUT + 4 * li);
    const float4 vs = *reinterpret_cast<const float4*>(
        hvb + (size_t)s * D_OUT + 4 * li);
    float p = ks.x * kd.x + ks.y * kd.y + ks.z * kd.z + ks.w * kd.w;
    p += __shfl_xor(p, 1, 64);
    p += __shfl_xor(p, 2, 64);
    p += __shfl_xor(p, 4, 64);
    p += __shfl_xor(p, 8, 64);
    const float mn = fmaxf(m, p);
    const float sc = __expf(m - mn);  // 0 on first edge (m=-FLT_MAX)
    const float a = __expf(p - mn);
    l = l * sc + a;
    acc.x = acc.x * sc + a * vs.x;
    acc.y = acc.y * sc + a * vs.y;
    acc.z = acc.z * sc + a * vs.z;
    acc.w = acc.w * sc + a * vs.w;
    m = mn;
  }
  // merge the 4 group states (flash-attention state merge, offsets 16,32)
#pragma unroll
  for (int off = 16; off <= 32; off <<= 1) {
    const float m2 = __shfl_xor(m, off, 64);
    const float l2 = __shfl_xor(l, off, 64);
    float4 a2;
    a2.x = __shfl_xor(acc.x, off, 64);
    a2.y = __shfl_xor(acc.y, off, 64);
    a2.z = __shfl_xor(acc.z, off, 64);
    a2.w = __shfl_xor(acc.w, off, 64);
    const float mn = fmaxf(m, m2);
    const float s1 = __expf(m - mn);
    const float s2 = __expf(m2 - mn);
    l = l * s1 + l2 * s2;
    acc.x = acc.x * s1 + a2.x * s2;
    acc.y = acc.y * s1 + a2.y * s2;
    acc.z = acc.z * s1 + a2.z * s2;
    acc.w = acc.w * s1 + a2.w * s2;
    m = mn;
  }
  if (lane < 16) {
    const float denom = (l == 0.f) ? 1.f : l;
    float4 o;
    o.x = acc.x / denom;
    o.y = acc.y / denom;
    o.z = acc.z / denom;
    o.w = acc.w / denom;
    o.x = (o.x >= 0.f) ? o.x : NEG_SLOPE * o.x;
    o.y = (o.y >= 0.f) ? o.y : NEG_SLOPE * o.y;
    o.z = (o.z >= 0.f) ? o.z : NEG_SLOPE * o.z;
    o.w = (o.w >= 0.f) ? o.w : NEG_SLOPE * o.w;
    *reinterpret_cast<float4*>(out + (size_t)w * D_OUT + 4 * lane) = o;
  }
}

// ---------------------------------------------------------------------------
extern "C" void kernel_launch(void* const* d_in, const int* in_sizes, int n_in,
                              void* d_out, int out_size, void* d_ws,
                              size_t ws_size, hipStream_t stream) {
  const float* X_key   = (const float*)d_in[0];
  const float* X_value = (const float*)d_in[1];
  const float* Wk      = (const float*)d_in[2];
  const float* bk      = (const float*)d_in[3];
  const float* Wv      = (const float*)d_in[4];
  const float* bv      = (const float*)d_in[5];
  const int*   src     = (const int*)d_in[6];
  const int*   dst     = (const int*)d_in[7];
  float* out = (float*)d_out;

  const int B = 2;
  const int R = in_sizes[0] / D_IN;  // B*N rows
  const int N = R / B;
  const int E = in_sizes[6];

  // workspace layout: hk [R*64] f32 | hv [R*64] f32 | row_ptr [N+1] i32
  float* hk = (float*)d_ws;
  float* hv = hk + (size_t)R * D_OUT;
  int* row_ptr = (int*)(hv + (size_t)R * D_OUT);

  const int wavesA = (R + RPW - 1) / RPW;
  const int blocksA = (wavesA + 3) / 4;
  hipLaunchKernelGGL(linear_kernel, dim3(blocksA), dim3(256), 0, stream,
                     X_key, Wk, bk, hk, R);
  hipLaunchKernelGGL(linear_kernel, dim3(blocksA), dim3(256), 0, stream,
                     X_value, Wv, bv, hv, R);
  const int blocksB = (N + 1 + 255) / 256;
  hipLaunchKernelGGL(rowptr_kernel, dim3(blocksB), dim3(256), 0, stream,
                     dst, E, N, row_ptr);
  const int blocksC = (R + 3) / 4;  // one wave per (b,node)
  hipLaunchKernelGGL(aggregate_kernel, dim3(blocksC), dim3(256), 0, stream,
                     hk, hv, src, row_ptr, out, N, B);
}

// Round 3
// 185.189 us; speedup vs baseline: 2.2774x; 2.2464x over previous
//
#include <hip/hip_runtime.h>
#include <cfloat>
#include <math.h>

#define D_IN 128
#define D_OUT 64
#define NEG_SLOPE 0.2f
#define TM 64  // rows per block in linear kernel

// ---------------------------------------------------------------------------
// Kernel A: H = X @ W + b.   X:[R,128] f32, W:[128,64], b:[64], H:[R,64]
// Register-tiled: thread (tc=t&15, tr=t>>4) computes rows 4*tr..+3 x cols
// 4*tc..+3 (acc[4][4]). W in LDS ([k][col], b128 reads, 2-way conflict max).
// X streamed from global: 4 rows x float4 per k-quad; 16 tc-threads share the
// same row lines -> L1 broadcast, each row pulled once per block from HBM.
// ---------------------------------------------------------------------------
__global__ __launch_bounds__(256) void linear_kernel(
    const float* __restrict__ X, const float* __restrict__ W,
    const float* __restrict__ b, float* __restrict__ H, int R) {
  __shared__ float Wl[D_IN * D_OUT];  // 32 KB, [k][col]
  __shared__ float bl[D_OUT];
  for (int i = threadIdx.x; i < D_IN * D_OUT / 4; i += 256)
    reinterpret_cast<float4*>(Wl)[i] = reinterpret_cast<const float4*>(W)[i];
  if (threadIdx.x < D_OUT) bl[threadIdx.x] = b[threadIdx.x];
  __syncthreads();

  const int tc = threadIdx.x & 15;   // col quad: cols 4*tc..4*tc+3
  const int tr = threadIdx.x >> 4;   // row quad: rows r0..r0+3
  const int r0 = blockIdx.x * TM + tr * 4;
  if (r0 >= R) return;

  const float4 bv = reinterpret_cast<float4*>(bl)[tc];
  float acc[4][4];
#pragma unroll
  for (int i = 0; i < 4; ++i) {
    acc[i][0] = bv.x; acc[i][1] = bv.y; acc[i][2] = bv.z; acc[i][3] = bv.w;
  }

  if (r0 + 4 <= R) {
    const float4* x0 = reinterpret_cast<const float4*>(X + (size_t)(r0 + 0) * D_IN);
    const float4* x1 = reinterpret_cast<const float4*>(X + (size_t)(r0 + 1) * D_IN);
    const float4* x2 = reinterpret_cast<const float4*>(X + (size_t)(r0 + 2) * D_IN);
    const float4* x3 = reinterpret_cast<const float4*>(X + (size_t)(r0 + 3) * D_IN);
    for (int k4 = 0; k4 < D_IN / 4; ++k4) {
      float4 xv[4];
      xv[0] = x0[k4]; xv[1] = x1[k4]; xv[2] = x2[k4]; xv[3] = x3[k4];
      const float4 w0 = reinterpret_cast<const float4*>(Wl + (k4 * 4 + 0) * D_OUT)[tc];
      const float4 w1 = reinterpret_cast<const float4*>(Wl + (k4 * 4 + 1) * D_OUT)[tc];
      const float4 w2 = reinterpret_cast<const float4*>(Wl + (k4 * 4 + 2) * D_OUT)[tc];
      const float4 w3 = reinterpret_cast<const float4*>(Wl + (k4 * 4 + 3) * D_OUT)[tc];
#pragma unroll
      for (int i = 0; i < 4; ++i) {
        acc[i][0] += xv[i].x * w0.x + xv[i].y * w1.x + xv[i].z * w2.x + xv[i].w * w3.x;
        acc[i][1] += xv[i].x * w0.y + xv[i].y * w1.y + xv[i].z * w2.y + xv[i].w * w3.y;
        acc[i][2] += xv[i].x * w0.z + xv[i].y * w1.z + xv[i].z * w2.z + xv[i].w * w3.z;
        acc[i][3] += xv[i].x * w0.w + xv[i].y * w1.w + xv[i].z * w2.w + xv[i].w * w3.w;
      }
    }
#pragma unroll
    for (int i = 0; i < 4; ++i) {
      float4 o = {acc[i][0], acc[i][1], acc[i][2], acc[i][3]};
      reinterpret_cast<float4*>(H + (size_t)(r0 + i) * D_OUT)[tc] = o;
    }
  } else {
    // guarded tail (rows r0..R-1)
    for (int i = 0; i < 4; ++i) {
      const int r = r0 + i;
      if (r >= R) break;
      float a0 = bv.x, a1 = bv.y, a2 = bv.z, a3 = bv.w;
      const float4* xr = reinterpret_cast<const float4*>(X + (size_t)r * D_IN);
      for (int k4 = 0; k4 < D_IN / 4; ++k4) {
        const float4 xv = xr[k4];
        const float4 w0 = reinterpret_cast<const float4*>(Wl + (k4 * 4 + 0) * D_OUT)[tc];
        const float4 w1 = reinterpret_cast<const float4*>(Wl + (k4 * 4 + 1) * D_OUT)[tc];
        const float4 w2 = reinterpret_cast<const float4*>(Wl + (k4 * 4 + 2) * D_OUT)[tc];
        const float4 w3 = reinterpret_cast<const float4*>(Wl + (k4 * 4 + 3) * D_OUT)[tc];
        a0 += xv.x * w0.x + xv.y * w1.x + xv.z * w2.x + xv.w * w3.x;
        a1 += xv.x * w0.y + xv.y * w1.y + xv.z * w2.y + xv.w * w3.y;
        a2 += xv.x * w0.z + xv.y * w1.z + xv.z * w2.z + xv.w * w3.z;
        a3 += xv.x * w0.w + xv.y * w1.w + xv.z * w2.w + xv.w * w3.w;
      }
      float4 o = {a0, a1, a2, a3};
      reinterpret_cast<float4*>(H + (size_t)r * D_OUT)[tc] = o;
    }
  }
}

// ---------------------------------------------------------------------------
// Kernel B: CSR row pointers from sorted dst. row_ptr[i] = lower_bound(dst, i)
// ---------------------------------------------------------------------------
__global__ void rowptr_kernel(const int* __restrict__ dst, int E, int N,
                              int* __restrict__ row_ptr) {
  int i = blockIdx.x * blockDim.x + threadIdx.x;
  if (i > N) return;
  int lo = 0, hi = E;
  while (lo < hi) {
    int mid = (lo + hi) >> 1;
    if (dst[mid] < i) lo = mid + 1; else hi = mid;
  }
  row_ptr[i] = lo;
}

// ---------------------------------------------------------------------------
// Kernel C: per-(batch,node) segmented online-softmax aggregation.
// One wave per (b,node); 4 groups of 16 lanes, each group owns every 4th
// edge with its own online-softmax state (4x ILP on the serial chain).
// Lane holds float4 of dims (16 lanes x 4 = 64). Dot reduce = 4 shfl steps.
// Branchless online update; 2-step cross-group state merge at the end.
// ---------------------------------------------------------------------------
__global__ __launch_bounds__(256) void aggregate_kernel(
    const float* __restrict__ hk, const float* __restrict__ hv,
    const int* __restrict__ src, const int* __restrict__ row_ptr,
    float* __restrict__ out, int N, int B) {
  const int w = blockIdx.x * 4 + (threadIdx.x >> 6);
  const int lane = threadIdx.x & 63;
  if (w >= B * N) return;
  int b = 0, node = w;
  while (node >= N) { node -= N; ++b; }
  const float* hkb = hk + (size_t)b * N * D_OUT;
  const float* hvb = hv + (size_t)b * N * D_OUT;

  const int li = lane & 15;  // dim-quad index
  const int g = lane >> 4;   // edge group

  const float4 kd = *reinterpret_cast<const float4*>(
      hkb + (size_t)node * D_OUT + 4 * li);
  const int e0 = row_ptr[node];
  const int e1 = row_ptr[node + 1];

  float m = -FLT_MAX, l = 0.f;
  float4 acc = {0.f, 0.f, 0.f, 0.f};
  for (int e = e0 + g; e < e1; e += 4) {
    const int s = src[e];
    const float4 ks = *reinterpret_cast<const float4*>(
        hkb + (size_t)s * D_OUT + 4 * li);
    const float4 vs = *reinterpret_cast<const float4*>(
        hvb + (size_t)s * D_OUT + 4 * li);
    float p = ks.x * kd.x + ks.y * kd.y + ks.z * kd.z + ks.w * kd.w;
    p += __shfl_xor(p, 1, 64);
    p += __shfl_xor(p, 2, 64);
    p += __shfl_xor(p, 4, 64);
    p += __shfl_xor(p, 8, 64);
    const float mn = fmaxf(m, p);
    const float sc = __expf(m - mn);  // 0 on first edge (m=-FLT_MAX)
    const float a = __expf(p - mn);
    l = l * sc + a;
    acc.x = acc.x * sc + a * vs.x;
    acc.y = acc.y * sc + a * vs.y;
    acc.z = acc.z * sc + a * vs.z;
    acc.w = acc.w * sc + a * vs.w;
    m = mn;
  }
  // merge the 4 group states (flash-attention state merge, offsets 16,32)
#pragma unroll
  for (int off = 16; off <= 32; off <<= 1) {
    const float m2 = __shfl_xor(m, off, 64);
    const float l2 = __shfl_xor(l, off, 64);
    float4 a2;
    a2.x = __shfl_xor(acc.x, off, 64);
    a2.y = __shfl_xor(acc.y, off, 64);
    a2.z = __shfl_xor(acc.z, off, 64);
    a2.w = __shfl_xor(acc.w, off, 64);
    const float mn = fmaxf(m, m2);
    const float s1 = __expf(m - mn);
    const float s2 = __expf(m2 - mn);
    l = l * s1 + l2 * s2;
    acc.x = acc.x * s1 + a2.x * s2;
    acc.y = acc.y * s1 + a2.y * s2;
    acc.z = acc.z * s1 + a2.z * s2;
    acc.w = acc.w * s1 + a2.w * s2;
    m = mn;
  }
  if (lane < 16) {
    const float denom = (l == 0.f) ? 1.f : l;
    float4 o;
    o.x = acc.x / denom;
    o.y = acc.y / denom;
    o.z = acc.z / denom;
    o.w = acc.w / denom;
    o.x = (o.x >= 0.f) ? o.x : NEG_SLOPE * o.x;
    o.y = (o.y >= 0.f) ? o.y : NEG_SLOPE * o.y;
    o.z = (o.z >= 0.f) ? o.z : NEG_SLOPE * o.z;
    o.w = (o.w >= 0.f) ? o.w : NEG_SLOPE * o.w;
    *reinterpret_cast<float4*>(out + (size_t)w * D_OUT + 4 * lane) = o;
  }
}

// ---------------------------------------------------------------------------
extern "C" void kernel_launch(void* const* d_in, const int* in_sizes, int n_in,
                              void* d_out, int out_size, void* d_ws,
                              size_t ws_size, hipStream_t stream) {
  const float* X_key   = (const float*)d_in[0];
  const float* X_value = (const float*)d_in[1];
  const float* Wk      = (const float*)d_in[2];
  const float* bk      = (const float*)d_in[3];
  const float* Wv      = (const float*)d_in[4];
  const float* bv      = (const float*)d_in[5];
  const int*   src     = (const int*)d_in[6];
  const int*   dst     = (const int*)d_in[7];
  float* out = (float*)d_out;

  const int B = 2;
  const int R = in_sizes[0] / D_IN;  // B*N rows
  const int N = R / B;
  const int E = in_sizes[6];

  // workspace layout: hk [R*64] f32 | hv [R*64] f32 | row_ptr [N+1] i32
  float* hk = (float*)d_ws;
  float* hv = hk + (size_t)R * D_OUT;
  int* row_ptr = (int*)(hv + (size_t)R * D_OUT);

  const int blocksA = (R + TM - 1) / TM;
  hipLaunchKernelGGL(linear_kernel, dim3(blocksA), dim3(256), 0, stream,
                     X_key, Wk, bk, hk, R);
  hipLaunchKernelGGL(linear_kernel, dim3(blocksA), dim3(256), 0, stream,
                     X_value, Wv, bv, hv, R);
  const int blocksB = (N + 1 + 255) / 256;
  hipLaunchKernelGGL(rowptr_kernel, dim3(blocksB), dim3(256), 0, stream,
                     dst, E, N, row_ptr);
  const int blocksC = (R + 3) / 4;  // one wave per (b,node)
  hipLaunchKernelGGL(aggregate_kernel, dim3(blocksC), dim3(256), 0, stream,
                     hk, hv, src, row_ptr, out, N, B);
}

// Round 4
// 183.790 us; speedup vs baseline: 2.2947x; 1.0076x over previous
//
#include <hip/hip_runtime.h>
#include <cfloat>
#include <math.h>

#define D_IN 128
#define D_OUT 64
#define NEG_SLOPE 0.2f
#define TM 64  // rows per block in linear kernel

// ---------------------------------------------------------------------------
// Kernel A: H = X @ W + b.   X:[R,128] f32, W:[128,64], b:[64], H:[R,64]
// Register-tiled: thread (tc=t&15, tr=t>>4) computes rows 4*tr..+3 x cols
// 4*tc..+3 (acc[4][4]). W in LDS ([k][col], b128 reads).
// ---------------------------------------------------------------------------
__global__ __launch_bounds__(256) void linear_kernel(
    const float* __restrict__ X, const float* __restrict__ W,
    const float* __restrict__ b, float* __restrict__ H, int R) {
  __shared__ float Wl[D_IN * D_OUT];  // 32 KB, [k][col]
  __shared__ float bl[D_OUT];
  for (int i = threadIdx.x; i < D_IN * D_OUT / 4; i += 256)
    reinterpret_cast<float4*>(Wl)[i] = reinterpret_cast<const float4*>(W)[i];
  if (threadIdx.x < D_OUT) bl[threadIdx.x] = b[threadIdx.x];
  __syncthreads();

  const int tc = threadIdx.x & 15;   // col quad: cols 4*tc..4*tc+3
  const int tr = threadIdx.x >> 4;   // row quad: rows r0..r0+3
  const int r0 = blockIdx.x * TM + tr * 4;
  if (r0 >= R) return;

  const float4 bv = reinterpret_cast<float4*>(bl)[tc];
  float acc[4][4];
#pragma unroll
  for (int i = 0; i < 4; ++i) {
    acc[i][0] = bv.x; acc[i][1] = bv.y; acc[i][2] = bv.z; acc[i][3] = bv.w;
  }

  if (r0 + 4 <= R) {
    const float4* x0 = reinterpret_cast<const float4*>(X + (size_t)(r0 + 0) * D_IN);
    const float4* x1 = reinterpret_cast<const float4*>(X + (size_t)(r0 + 1) * D_IN);
    const float4* x2 = reinterpret_cast<const float4*>(X + (size_t)(r0 + 2) * D_IN);
    const float4* x3 = reinterpret_cast<const float4*>(X + (size_t)(r0 + 3) * D_IN);
    for (int k4 = 0; k4 < D_IN / 4; ++k4) {
      float4 xv[4];
      xv[0] = x0[k4]; xv[1] = x1[k4]; xv[2] = x2[k4]; xv[3] = x3[k4];
      const float4 w0 = reinterpret_cast<const float4*>(Wl + (k4 * 4 + 0) * D_OUT)[tc];
      const float4 w1 = reinterpret_cast<const float4*>(Wl + (k4 * 4 + 1) * D_OUT)[tc];
      const float4 w2 = reinterpret_cast<const float4*>(Wl + (k4 * 4 + 2) * D_OUT)[tc];
      const float4 w3 = reinterpret_cast<const float4*>(Wl + (k4 * 4 + 3) * D_OUT)[tc];
#pragma unroll
      for (int i = 0; i < 4; ++i) {
        acc[i][0] += xv[i].x * w0.x + xv[i].y * w1.x + xv[i].z * w2.x + xv[i].w * w3.x;
        acc[i][1] += xv[i].x * w0.y + xv[i].y * w1.y + xv[i].z * w2.y + xv[i].w * w3.y;
        acc[i][2] += xv[i].x * w0.z + xv[i].y * w1.z + xv[i].z * w2.z + xv[i].w * w3.z;
        acc[i][3] += xv[i].x * w0.w + xv[i].y * w1.w + xv[i].z * w2.w + xv[i].w * w3.w;
      }
    }
#pragma unroll
    for (int i = 0; i < 4; ++i) {
      float4 o = {acc[i][0], acc[i][1], acc[i][2], acc[i][3]};
      reinterpret_cast<float4*>(H + (size_t)(r0 + i) * D_OUT)[tc] = o;
    }
  } else {
    for (int i = 0; i < 4; ++i) {
      const int r = r0 + i;
      if (r >= R) break;
      float a0 = bv.x, a1 = bv.y, a2 = bv.z, a3 = bv.w;
      const float4* xr = reinterpret_cast<const float4*>(X + (size_t)r * D_IN);
      for (int k4 = 0; k4 < D_IN / 4; ++k4) {
        const float4 xv = xr[k4];
        const float4 w0 = reinterpret_cast<const float4*>(Wl + (k4 * 4 + 0) * D_OUT)[tc];
        const float4 w1 = reinterpret_cast<const float4*>(Wl + (k4 * 4 + 1) * D_OUT)[tc];
        const float4 w2 = reinterpret_cast<const float4*>(Wl + (k4 * 4 + 2) * D_OUT)[tc];
        const float4 w3 = reinterpret_cast<const float4*>(Wl + (k4 * 4 + 3) * D_OUT)[tc];
        a0 += xv.x * w0.x + xv.y * w1.x + xv.z * w2.x + xv.w * w3.x;
        a1 += xv.x * w0.y + xv.y * w1.y + xv.z * w2.y + xv.w * w3.y;
        a2 += xv.x * w0.z + xv.y * w1.z + xv.z * w2.z + xv.w * w3.z;
        a3 += xv.x * w0.w + xv.y * w1.w + xv.z * w2.w + xv.w * w3.w;
      }
      float4 o = {a0, a1, a2, a3};
      reinterpret_cast<float4*>(H + (size_t)r * D_OUT)[tc] = o;
    }
  }
}

// ---------------------------------------------------------------------------
// Kernel B: CSR row pointers from sorted dst. row_ptr[i] = lower_bound(dst, i)
// ---------------------------------------------------------------------------
__global__ void rowptr_kernel(const int* __restrict__ dst, int E, int N,
                              int* __restrict__ row_ptr) {
  int i = blockIdx.x * blockDim.x + threadIdx.x;
  if (i > N) return;
  int lo = 0, hi = E;
  while (lo < hi) {
    int mid = (lo + hi) >> 1;
    if (dst[mid] < i) lo = mid + 1; else hi = mid;
  }
  row_ptr[i] = lo;
}

// ---------------------------------------------------------------------------
// sum over each 16-lane row via DPP rotate-adds (pure VALU — no LDS pipe,
// ~4-8 cyc/step vs ~30-60 for ds_swizzle-based __shfl_xor).
// ---------------------------------------------------------------------------
__device__ __forceinline__ float rowsum16(float p) {
  union { float f; int i; } u, v;
#pragma unroll
  for (int ctrl = 0x121; ctrl <= 0x128; ctrl <<= 0) {  // placeholder, unrolled below
    break;
  }
  u.f = p;
  v.i = __builtin_amdgcn_update_dpp(0, u.i, 0x121, 0xF, 0xF, true);  // row_ror:1
  u.f += v.f;
  v.i = __builtin_amdgcn_update_dpp(0, u.i, 0x122, 0xF, 0xF, true);  // row_ror:2
  u.f += v.f;
  v.i = __builtin_amdgcn_update_dpp(0, u.i, 0x124, 0xF, 0xF, true);  // row_ror:4
  u.f += v.f;
  v.i = __builtin_amdgcn_update_dpp(0, u.i, 0x128, 0xF, 0xF, true);  // row_ror:8
  u.f += v.f;
  return u.f;
}

// ---------------------------------------------------------------------------
// Kernel C: per-(batch,node) segmented online-softmax aggregation.
// One wave per (b,node); 4 groups of 16 lanes; each group keeps TWO
// independent online-softmax states (edges e, e+4 per iteration) -> 8
// concurrent edge-chains per wave. 16-lane dot reduce via DPP rotate-adds.
// ---------------------------------------------------------------------------
__global__ __launch_bounds__(256) void aggregate_kernel(
    const float* __restrict__ hk, const float* __restrict__ hv,
    const int* __restrict__ src, const int* __restrict__ row_ptr,
    float* __restrict__ out, int N, int B) {
  const int w = blockIdx.x * 4 + (threadIdx.x >> 6);
  const int lane = threadIdx.x & 63;
  if (w >= B * N) return;
  int b = 0, node = w;
  while (node >= N) { node -= N; ++b; }
  const float* hkb = hk + (size_t)b * N * D_OUT;
  const float* hvb = hv + (size_t)b * N * D_OUT;

  const int li = lane & 15;  // dim-quad index
  const int g = lane >> 4;   // edge group

  const float4 kd = *reinterpret_cast<const float4*>(
      hkb + (size_t)node * D_OUT + 4 * li);
  const int e0 = row_ptr[node];
  const int e1 = row_ptr[node + 1];

  float mA = -FLT_MAX, lA = 0.f, mB = -FLT_MAX, lB = 0.f;
  float4 aA = {0.f, 0.f, 0.f, 0.f}, aB = {0.f, 0.f, 0.f, 0.f};

#define PROC(EIDX, m, l, acc)                                                  \
  {                                                                            \
    const int s = src[EIDX];                                                   \
    const float4 ks = *reinterpret_cast<const float4*>(                        \
        hkb + (size_t)s * D_OUT + 4 * li);                                     \
    const float4 vs = *reinterpret_cast<const float4*>(                        \
        hvb + (size_t)s * D_OUT + 4 * li);                                     \
    float p = ks.x * kd.x + ks.y * kd.y + ks.z * kd.z + ks.w * kd.w;           \
    p = rowsum16(p);                                                           \
    const float mn = fmaxf(m, p);                                              \
    const float sc = __expf(m - mn);                                           \
    const float a = __expf(p - mn);                                            \
    l = l * sc + a;                                                            \
    acc.x = acc.x * sc + a * vs.x;                                             \
    acc.y = acc.y * sc + a * vs.y;                                             \
    acc.z = acc.z * sc + a * vs.z;                                             \
    acc.w = acc.w * sc + a * vs.w;                                             \
    m = mn;                                                                    \
  }

  int e = e0 + g;
  for (; e + 4 < e1; e += 8) {
    PROC(e, mA, lA, aA);
    PROC(e + 4, mB, lB, aB);
  }
  if (e < e1) PROC(e, mA, lA, aA);
#undef PROC

  // merge state B into A (handles empty B: lB=0 contributes 0)
  {
    const float mn = fmaxf(mA, mB);
    const float s1 = __expf(mA - mn);
    const float s2 = __expf(mB - mn);
    lA = lA * s1 + lB * s2;
    aA.x = aA.x * s1 + aB.x * s2;
    aA.y = aA.y * s1 + aB.y * s2;
    aA.z = aA.z * s1 + aB.z * s2;
    aA.w = aA.w * s1 + aB.w * s2;
    mA = mn;
  }
  // merge the 4 group states (offsets 16, 32)
#pragma unroll
  for (int off = 16; off <= 32; off <<= 1) {
    const float m2 = __shfl_xor(mA, off, 64);
    const float l2 = __shfl_xor(lA, off, 64);
    float4 a2;
    a2.x = __shfl_xor(aA.x, off, 64);
    a2.y = __shfl_xor(aA.y, off, 64);
    a2.z = __shfl_xor(aA.z, off, 64);
    a2.w = __shfl_xor(aA.w, off, 64);
    const float mn = fmaxf(mA, m2);
    const float s1 = __expf(mA - mn);
    const float s2 = __expf(m2 - mn);
    lA = lA * s1 + l2 * s2;
    aA.x = aA.x * s1 + a2.x * s2;
    aA.y = aA.y * s1 + a2.y * s2;
    aA.z = aA.z * s1 + a2.z * s2;
    aA.w = aA.w * s1 + a2.w * s2;
    mA = mn;
  }
  if (lane < 16) {
    const float denom = (lA == 0.f) ? 1.f : lA;
    float4 o;
    o.x = aA.x / denom;
    o.y = aA.y / denom;
    o.z = aA.z / denom;
    o.w = aA.w / denom;
    o.x = (o.x >= 0.f) ? o.x : NEG_SLOPE * o.x;
    o.y = (o.y >= 0.f) ? o.y : NEG_SLOPE * o.y;
    o.z = (o.z >= 0.f) ? o.z : NEG_SLOPE * o.z;
    o.w = (o.w >= 0.f) ? o.w : NEG_SLOPE * o.w;
    *reinterpret_cast<float4*>(out + (size_t)w * D_OUT + 4 * lane) = o;
  }
}

// ---------------------------------------------------------------------------
extern "C" void kernel_launch(void* const* d_in, const int* in_sizes, int n_in,
                              void* d_out, int out_size, void* d_ws,
                              size_t ws_size, hipStream_t stream) {
  const float* X_key   = (const float*)d_in[0];
  const float* X_value = (const float*)d_in[1];
  const float* Wk      = (const float*)d_in[2];
  const float* bk      = (const float*)d_in[3];
  const float* Wv      = (const float*)d_in[4];
  const float* bv      = (const float*)d_in[5];
  const int*   src     = (const int*)d_in[6];
  const int*   dst     = (const int*)d_in[7];
  float* out = (float*)d_out;

  const int B = 2;
  const int R = in_sizes[0] / D_IN;  // B*N rows
  const int N = R / B;
  const int E = in_sizes[6];

  // workspace layout: hk [R*64] f32 | hv [R*64] f32 | row_ptr [N+1] i32
  float* hk = (float*)d_ws;
  float* hv = hk + (size_t)R * D_OUT;
  int* row_ptr = (int*)(hv + (size_t)R * D_OUT);

  const int blocksB = (N + 1 + 255) / 256;
  hipLaunchKernelGGL(rowptr_kernel, dim3(blocksB), dim3(256), 0, stream,
                     dst, E, N, row_ptr);
  const int blocksA = (R + TM - 1) / TM;
  hipLaunchKernelGGL(linear_kernel, dim3(blocksA), dim3(256), 0, stream,
                     X_key, Wk, bk, hk, R);
  hipLaunchKernelGGL(linear_kernel, dim3(blocksA), dim3(256), 0, stream,
                     X_value, Wv, bv, hv, R);
  const int blocksC = (R + 3) / 4;  // one wave per (b,node)
  hipLaunchKernelGGL(aggregate_kernel, dim3(blocksC), dim3(256), 0, stream,
                     hk, hv, src, row_ptr, out, N, B);
}

// Round 6
// 158.295 us; speedup vs baseline: 2.6643x; 1.1611x over previous
//
#include <hip/hip_runtime.h>
#include <cfloat>
#include <math.h>

#define D_IN 128
#define D_OUT 64
#define NEG_SLOPE 0.2f
#define TM 64    // rows per block in linear kernel
#define ROWF 96  // floats per hkv row: 64 f32 (hk) + 64 bf16 (hv) = 384 B

// bf16 pack (RNE) / unpack helpers --------------------------------------------
__device__ __forceinline__ unsigned short f2bf(float x) {
  union { float f; unsigned u; } a; a.f = x;
  unsigned r = a.u + 0x7FFFu + ((a.u >> 16) & 1u);
  return (unsigned short)(r >> 16);
}
__device__ __forceinline__ float4 unpack4(uint2 q) {
  union { unsigned u; float f; } t;
  float4 r;
  t.u = q.x << 16;          r.x = t.f;
  t.u = q.x & 0xFFFF0000u;  r.y = t.f;
  t.u = q.y << 16;          r.z = t.f;
  t.u = q.y & 0xFFFF0000u;  r.w = t.f;
  return r;
}

// ---------------------------------------------------------------------------
// Kernel A (fused K+V): H = X @ W + b.
// Row layout: hkv[r] = [64 f32 of hk | 64 bf16 of hv]  (384 B, 3 cache lines)
// blockIdx < nblk: key half (f32), else value half (bf16).
// Register-tiled: thread (tc=t&15, tr=t>>4) computes 4 rows x 4 cols.
// ---------------------------------------------------------------------------
__global__ __launch_bounds__(256) void linear_kernel(
    const float* __restrict__ Xk, const float* __restrict__ Xv,
    const float* __restrict__ Wk, const float* __restrict__ bk,
    const float* __restrict__ Wv, const float* __restrict__ bv,
    float* __restrict__ hkv, int R, int nblk) {
  const int which = (blockIdx.x >= nblk) ? 1 : 0;
  const int blk = blockIdx.x - which * nblk;
  const float* __restrict__ X = which ? Xv : Xk;
  const float* __restrict__ W = which ? Wv : Wk;
  const float* __restrict__ bias = which ? bv : bk;

  __shared__ float Wl[D_IN * D_OUT];  // 32 KB, [k][col]
  __shared__ float bl[D_OUT];
  for (int i = threadIdx.x; i < D_IN * D_OUT / 4; i += 256)
    reinterpret_cast<float4*>(Wl)[i] = reinterpret_cast<const float4*>(W)[i];
  if (threadIdx.x < D_OUT) bl[threadIdx.x] = bias[threadIdx.x];
  __syncthreads();

  const int tc = threadIdx.x & 15;   // col quad
  const int tr = threadIdx.x >> 4;   // row quad
  const int r0 = blk * TM + tr * 4;
  if (r0 >= R) return;

  const float4 bv4 = reinterpret_cast<float4*>(bl)[tc];
  float acc[4][4];
#pragma unroll
  for (int i = 0; i < 4; ++i) {
    acc[i][0] = bv4.x; acc[i][1] = bv4.y; acc[i][2] = bv4.z; acc[i][3] = bv4.w;
  }

  const int rmax = (r0 + 4 <= R) ? 4 : (R - r0);
  const float4* xr[4];
#pragma unroll
  for (int i = 0; i < 4; ++i)
    xr[i] = reinterpret_cast<const float4*>(
        X + (size_t)(r0 + (i < rmax ? i : 0)) * D_IN);

  for (int k4 = 0; k4 < D_IN / 4; ++k4) {
    float4 xv[4];
#pragma unroll
    for (int i = 0; i < 4; ++i) xv[i] = xr[i][k4];
    const float4 w0 = reinterpret_cast<const float4*>(Wl + (k4 * 4 + 0) * D_OUT)[tc];
    const float4 w1 = reinterpret_cast<const float4*>(Wl + (k4 * 4 + 1) * D_OUT)[tc];
    const float4 w2 = reinterpret_cast<const float4*>(Wl + (k4 * 4 + 2) * D_OUT)[tc];
    const float4 w3 = reinterpret_cast<const float4*>(Wl + (k4 * 4 + 3) * D_OUT)[tc];
#pragma unroll
    for (int i = 0; i < 4; ++i) {
      acc[i][0] += xv[i].x * w0.x + xv[i].y * w1.x + xv[i].z * w2.x + xv[i].w * w3.x;
      acc[i][1] += xv[i].x * w0.y + xv[i].y * w1.y + xv[i].z * w2.y + xv[i].w * w3.y;
      acc[i][2] += xv[i].x * w0.z + xv[i].y * w1.z + xv[i].z * w2.z + xv[i].w * w3.z;
      acc[i][3] += xv[i].x * w0.w + xv[i].y * w1.w + xv[i].z * w2.w + xv[i].w * w3.w;
    }
  }
#pragma unroll
  for (int i = 0; i < 4; ++i) {
    if (i >= rmax) break;
    float* row = hkv + (size_t)(r0 + i) * ROWF;
    if (which == 0) {
      float4 o = {acc[i][0], acc[i][1], acc[i][2], acc[i][3]};
      reinterpret_cast<float4*>(row)[tc] = o;
    } else {
      ushort4 o;
      o.x = f2bf(acc[i][0]); o.y = f2bf(acc[i][1]);
      o.z = f2bf(acc[i][2]); o.w = f2bf(acc[i][3]);
      *reinterpret_cast<ushort4*>(
          reinterpret_cast<unsigned short*>(row + D_OUT) + 4 * tc) = o;
    }
  }
}

// ---------------------------------------------------------------------------
// Kernel B: CSR row pointers from sorted dst. row_ptr[i] = lower_bound(dst, i)
// ---------------------------------------------------------------------------
__global__ void rowptr_kernel(const int* __restrict__ dst, int E, int N,
                              int* __restrict__ row_ptr) {
  int i = blockIdx.x * blockDim.x + threadIdx.x;
  if (i > N) return;
  int lo = 0, hi = E;
  while (lo < hi) {
    int mid = (lo + hi) >> 1;
    if (dst[mid] < i) lo = mid + 1; else hi = mid;
  }
  row_ptr[i] = lo;
}

// ---------------------------------------------------------------------------
// sum over each 16-lane row via DPP rotate-adds (pure VALU).
// ---------------------------------------------------------------------------
__device__ __forceinline__ float rowsum16(float p) {
  union { float f; int i; } u, v;
  u.f = p;
  v.i = __builtin_amdgcn_update_dpp(0, u.i, 0x121, 0xF, 0xF, true);  // row_ror:1
  u.f += v.f;
  v.i = __builtin_amdgcn_update_dpp(0, u.i, 0x122, 0xF, 0xF, true);  // row_ror:2
  u.f += v.f;
  v.i = __builtin_amdgcn_update_dpp(0, u.i, 0x124, 0xF, 0xF, true);  // row_ror:4
  u.f += v.f;
  v.i = __builtin_amdgcn_update_dpp(0, u.i, 0x128, 0xF, 0xF, true);  // row_ror:8
  u.f += v.f;
  return u.f;
}

struct SMState { float m, l; float4 a; };

__device__ __forceinline__ void sm_update(SMState& st, float p, float4 vs) {
  const float mn = fmaxf(st.m, p);
  const float sc = __expf(st.m - mn);
  const float a = __expf(p - mn);
  st.l = st.l * sc + a;
  st.a.x = st.a.x * sc + a * vs.x;
  st.a.y = st.a.y * sc + a * vs.y;
  st.a.z = st.a.z * sc + a * vs.z;
  st.a.w = st.a.w * sc + a * vs.w;
  st.m = mn;
}

__device__ __forceinline__ void sm_merge(SMState& d, const SMState& s) {
  const float mn = fmaxf(d.m, s.m);
  const float s1 = __expf(d.m - mn);
  const float s2 = __expf(s.m - mn);
  d.l = d.l * s1 + s.l * s2;
  d.a.x = d.a.x * s1 + s.a.x * s2;
  d.a.y = d.a.y * s1 + s.a.y * s2;
  d.a.z = d.a.z * s1 + s.a.z * s2;
  d.a.w = d.a.w * s1 + s.a.w * s2;
  d.m = mn;
}

__device__ __forceinline__ void sm_merge_xor(SMState& d, int off) {
  SMState s;
  s.m = __shfl_xor(d.m, off, 64);
  s.l = __shfl_xor(d.l, off, 64);
  s.a.x = __shfl_xor(d.a.x, off, 64);
  s.a.y = __shfl_xor(d.a.y, off, 64);
  s.a.z = __shfl_xor(d.a.z, off, 64);
  s.a.w = __shfl_xor(d.a.w, off, 64);
  sm_merge(d, s);
}

__device__ __forceinline__ void edge_proc(const float* __restrict__ hb, int s,
                                          int li, const float4& kd,
                                          SMState& st) {
  const float* row = hb + (size_t)s * ROWF;
  const float4 ks = reinterpret_cast<const float4*>(row)[li];
  const float4 vs = unpack4(reinterpret_cast<const uint2*>(row + D_OUT)[li]);
  float p = ks.x * kd.x + ks.y * kd.y + ks.z * kd.z + ks.w * kd.w;
  p = rowsum16(p);
  sm_update(st, p, vs);
}

// ---------------------------------------------------------------------------
// Kernel C: per-node segmented online-softmax aggregation, BOTH batches per
// wave. 4 groups of 16 lanes; per group 2 ILP states x 2 batches = 4
// independent chains. hk gathered f32 (exact scores), hv bf16.
// ---------------------------------------------------------------------------
__global__ __launch_bounds__(256) void aggregate_kernel(
    const float* __restrict__ hkv, const int* __restrict__ src,
    const int* __restrict__ row_ptr, float* __restrict__ out, int N) {
  const int node = blockIdx.x * 4 + (threadIdx.x >> 6);
  const int lane = threadIdx.x & 63;
  if (node >= N) return;
  const float* hb0 = hkv;
  const float* hb1 = hkv + (size_t)N * ROWF;

  const int li = lane & 15;  // dim-quad index
  const int g = lane >> 4;   // edge group

  const float4 kd0 = reinterpret_cast<const float4*>(hb0 + (size_t)node * ROWF)[li];
  const float4 kd1 = reinterpret_cast<const float4*>(hb1 + (size_t)node * ROWF)[li];
  const int e0 = row_ptr[node];
  const int e1 = row_ptr[node + 1];

  SMState A0 = {-FLT_MAX, 0.f, {0.f, 0.f, 0.f, 0.f}};
  SMState B0 = A0, A1 = A0, B1 = A0;

  int e = e0 + g;
  for (; e + 4 < e1; e += 8) {
    const int sA = src[e];
    const int sB = src[e + 4];
    edge_proc(hb0, sA, li, kd0, A0);
    edge_proc(hb1, sA, li, kd1, A1);
    edge_proc(hb0, sB, li, kd0, B0);
    edge_proc(hb1, sB, li, kd1, B1);
  }
  if (e < e1) {
    const int sA = src[e];
    edge_proc(hb0, sA, li, kd0, A0);
    edge_proc(hb1, sA, li, kd1, A1);
  }

  sm_merge(A0, B0);
  sm_merge(A1, B1);
  sm_merge_xor(A0, 16); sm_merge_xor(A0, 32);
  sm_merge_xor(A1, 16); sm_merge_xor(A1, 32);

  if (lane < 16) {
#pragma unroll
    for (int b = 0; b < 2; ++b) {
      const SMState& S = b ? A1 : A0;
      const float denom = (S.l == 0.f) ? 1.f : S.l;
      float4 o;
      o.x = S.a.x / denom; o.y = S.a.y / denom;
      o.z = S.a.z / denom; o.w = S.a.w / denom;
      o.x = (o.x >= 0.f) ? o.x : NEG_SLOPE * o.x;
      o.y = (o.y >= 0.f) ? o.y : NEG_SLOPE * o.y;
      o.z = (o.z >= 0.f) ? o.z : NEG_SLOPE * o.z;
      o.w = (o.w >= 0.f) ? o.w : NEG_SLOPE * o.w;
      *reinterpret_cast<float4*>(out + ((size_t)b * N + node) * D_OUT + 4 * lane) = o;
    }
  }
}

// ---------------------------------------------------------------------------
extern "C" void kernel_launch(void* const* d_in, const int* in_sizes, int n_in,
                              void* d_out, int out_size, void* d_ws,
                              size_t ws_size, hipStream_t stream) {
  const float* X_key   = (const float*)d_in[0];
  const float* X_value = (const float*)d_in[1];
  const float* Wk      = (const float*)d_in[2];
  const float* bk      = (const float*)d_in[3];
  const float* Wv      = (const float*)d_in[4];
  const float* bv      = (const float*)d_in[5];
  const int*   src     = (const int*)d_in[6];
  const int*   dst     = (const int*)d_in[7];
  float* out = (float*)d_out;

  const int B = 2;
  const int R = in_sizes[0] / D_IN;  // B*N rows
  const int N = R / B;
  const int E = in_sizes[6];

  // workspace: hkv [R][96] f32-units (64 f32 hk | 64 bf16 hv) | row_ptr
  float* hkv = (float*)d_ws;
  int* row_ptr = (int*)(hkv + (size_t)R * ROWF);

  const int blocksB = (N + 1 + 255) / 256;
  hipLaunchKernelGGL(rowptr_kernel, dim3(blocksB), dim3(256), 0, stream,
                     dst, E, N, row_ptr);
  const int nblk = (R + TM - 1) / TM;
  hipLaunchKernelGGL(linear_kernel, dim3(2 * nblk), dim3(256), 0, stream,
                     X_key, X_value, Wk, bk, Wv, bv, hkv, R, nblk);
  const int blocksC = (N + 3) / 4;  // one wave per node, both batches
  hipLaunchKernelGGL(aggregate_kernel, dim3(blocksC), dim3(256), 0, stream,
                     hkv, src, row_ptr, out, N);
}